// Round 18
// baseline (100.665 us; speedup 1.0000x reference)
//
#include <hip/hip_runtime.h>

// B=256, F=32, N=16, D=512
//   sims[b,f,c,n] = relu(face[b,f]·ner[c,n])      (8192 x 4096 NT GEMM, K=512)
//   S_all[b,f]    = sum_{c,n} masked(sims)        (masked: ==1.0 -> 0)
//   pos[b,f]      = sum_n sims[b,f,b,n]           (unmasked diagonal)
//   diag_m[b,f]   = sum_n masked(sims[b,f,b,n])
//   loss = sum(relu((S_all-diag_m)/255 - pos + 0.2) * face_mask) / 256
//
// Round 18: r15 (best total, 63.19 us) + final-kernel FUSION via last-block
// atomic counter (device-scope atomics + __threadfence release/acquire).
// Removes one launch + inter-kernel gap. cvt zeroes the counter each call
// (deterministic across graph replays). Everything else byte-identical to
// r15's verified pipeline: r2 GEMM core, fused rowsum + diag epilogue,
// merged cvt+mask+memset.

#define DIM_D 512
#define M_TOT 8192
#define N_TOT 4096
#define NBLOCKS (64 * 32)

typedef __attribute__((ext_vector_type(8))) short short8v;
typedef __attribute__((ext_vector_type(4))) float f32x4;

__device__ __forceinline__ unsigned short f2bf(float f) {
  unsigned int u = __builtin_bit_cast(unsigned int, f);
  u += 0x7fffu + ((u >> 16) & 1u);
  return (unsigned short)(u >> 16);
}

// ---------------------------------------------------------------------------
// Merged cvt: face+ner fp32 -> bf16, face_mask, S_all zeroing, counter zero.
// ---------------------------------------------------------------------------
__global__ __launch_bounds__(256) void cvt_all(
    const float* __restrict__ face, const float* __restrict__ ner,
    unsigned short* __restrict__ face_bf, unsigned short* __restrict__ ner_bf,
    float* __restrict__ mask, float* __restrict__ S_all,
    unsigned int* __restrict__ counter) {
  if (blockIdx.x < 8) {  // 8 blocks x 256 thr x 4 floats = 8192 = S_all
    const int i = blockIdx.x * 1024 + threadIdx.x * 4;
    *(float4*)(S_all + i) = (float4){0.f, 0.f, 0.f, 0.f};
  }
  if (blockIdx.x == 8 && threadIdx.x == 0) *counter = 0u;

  const int gw = blockIdx.x * 4 + (threadIdx.x >> 6);
  const int lane = threadIdx.x & 63;
  const bool isFace = gw < M_TOT;
  const int row = isFace ? gw : gw - M_TOT;
  const float* src = (isFace ? face : ner) + (size_t)row * DIM_D;
  unsigned short* dst = (isFace ? face_bf : ner_bf) + (size_t)row * DIM_D;

  const float4 f0 = ((const float4*)src)[lane * 2];
  const float4 f1 = ((const float4*)src)[lane * 2 + 1];
  short8v o;
  o[0] = (short)f2bf(f0.x); o[1] = (short)f2bf(f0.y);
  o[2] = (short)f2bf(f0.z); o[3] = (short)f2bf(f0.w);
  o[4] = (short)f2bf(f1.x); o[5] = (short)f2bf(f1.y);
  o[6] = (short)f2bf(f1.z); o[7] = (short)f2bf(f1.w);
  *(short8v*)(dst + lane * 8) = o;

  if (isFace) {
    float fs = f0.x + f0.y + f0.z + f0.w + f1.x + f1.y + f1.z + f1.w;
#pragma unroll
    for (int off = 1; off < 64; off <<= 1) fs += __shfl_xor(fs, off);
    if (lane == 0) mask[row] = (fs != 0.0f) ? 1.0f : 0.0f;
  }
}

// ---------------------------------------------------------------------------
// r2's GEMM core (byte-identical to r15): 128x128 tile, BK=32, 4 waves (2x2),
// wave-tile 64x64 = 4x4 frags of 16x16. LDS 16 KB single-buffer, measured-0-
// conflict XOR k-slot swizzle, global_load_lds w=16 staging. Fused rowsum +
// diag epilogue + LAST-BLOCK loss reduction (atomic counter).
// ---------------------------------------------------------------------------
#define MFMA(A_, B_, C_) __builtin_amdgcn_mfma_f32_16x16x32_bf16(A_, B_, C_, 0, 0, 0)

__global__ __launch_bounds__(256) void grl_gemm_bf16(
    const unsigned short* __restrict__ A, const unsigned short* __restrict__ Bn,
    float* __restrict__ S_all, float* __restrict__ pos,
    float* __restrict__ diagm, const float* __restrict__ mask,
    unsigned int* __restrict__ counter, float* __restrict__ out) {
  __shared__ __align__(16) unsigned short As[128 * 32];
  __shared__ __align__(16) unsigned short Bs[128 * 32];
  __shared__ unsigned int lastFlag;
  __shared__ float red[4];

  const int tid = threadIdx.x;
  const int lane = tid & 63;
  const int wid = tid >> 6;
  const int wr = wid >> 1;        // wave row (0..1)
  const int wc = wid & 1;         // wave col (0..1)
  const int bx = blockIdx.x;
  const int by = blockIdx.y;
  const int m0 = bx * 128;
  const int n0 = by * 128;

  // ---- stager per-lane setup (2 instrs per matrix per wave) ----
  const int g = (lane & 3) ^ ((lane >> 3) & 3);
  const int r0 = wid * 32 + (lane >> 2);
  const int r1 = r0 + 16;
  const unsigned short* gA0 = A + (size_t)(m0 + r0) * DIM_D + g * 8;
  const unsigned short* gA1 = A + (size_t)(m0 + r1) * DIM_D + g * 8;
  const unsigned short* gB0 = Bn + (size_t)(n0 + r0) * DIM_D + g * 8;
  const unsigned short* gB1 = Bn + (size_t)(n0 + r1) * DIM_D + g * 8;
  unsigned short* lA0 = As + (wid * 2 + 0) * 512;   // wave-uniform LDS bases
  unsigned short* lA1 = As + (wid * 2 + 1) * 512;
  unsigned short* lB0 = Bs + (wid * 2 + 0) * 512;
  unsigned short* lB1 = Bs + (wid * 2 + 1) * 512;

  // ---- reader per-lane setup ----
  const int slotR = (lane >> 4) ^ ((lane >> 1) & 3);
  const int aoff = (lane & 15) * 32 + slotR * 8;   // in shorts (row stride 32)

  f32x4 acc[4][4];
#pragma unroll
  for (int i = 0; i < 4; ++i)
#pragma unroll
    for (int j = 0; j < 4; ++j) acc[i][j] = (f32x4){0.f, 0.f, 0.f, 0.f};

  for (int k0 = 0; k0 < DIM_D; k0 += 32) {
    __builtin_amdgcn_global_load_lds(
        (const __attribute__((address_space(1))) void*)(gA0 + k0),
        (__attribute__((address_space(3))) void*)lA0, 16, 0, 0);
    __builtin_amdgcn_global_load_lds(
        (const __attribute__((address_space(1))) void*)(gA1 + k0),
        (__attribute__((address_space(3))) void*)lA1, 16, 0, 0);
    __builtin_amdgcn_global_load_lds(
        (const __attribute__((address_space(1))) void*)(gB0 + k0),
        (__attribute__((address_space(3))) void*)lB0, 16, 0, 0);
    __builtin_amdgcn_global_load_lds(
        (const __attribute__((address_space(1))) void*)(gB1 + k0),
        (__attribute__((address_space(3))) void*)lB1, 16, 0, 0);
    __syncthreads();   // compiler drains vmcnt(0) here

    short8v af[4], bfr[4];
#pragma unroll
    for (int mi = 0; mi < 4; ++mi)
      af[mi] = *(const short8v*)(As + (wr * 64 + mi * 16) * 32 + aoff);
#pragma unroll
    for (int ni = 0; ni < 4; ++ni)
      bfr[ni] = *(const short8v*)(Bs + (wc * 64 + ni * 16) * 32 + aoff);
#pragma unroll
    for (int mi = 0; mi < 4; ++mi)
#pragma unroll
      for (int ni = 0; ni < 4; ++ni)
        acc[mi][ni] = MFMA(af[mi], bfr[ni], acc[mi][ni]);
    __syncthreads();
  }

  // ---- fused epilogue: relu, ==1->0, row sums ----
  // C/D layout (m89-verified): col = lane&15 (n), row = (lane>>4)*4 + reg
  float rsum[4][4];   // [mi][reg]
#pragma unroll
  for (int mi = 0; mi < 4; ++mi)
#pragma unroll
    for (int r = 0; r < 4; ++r) rsum[mi][r] = 0.0f;
#pragma unroll
  for (int mi = 0; mi < 4; ++mi)
#pragma unroll
    for (int ni = 0; ni < 4; ++ni)
#pragma unroll
      for (int r = 0; r < 4; ++r) {
        float v = acc[mi][ni][r];
        v = v > 0.0f ? v : 0.0f;
        v = (v == 1.0f) ? 0.0f : v;
        rsum[mi][r] += v;
      }

#pragma unroll
  for (int mi = 0; mi < 4; ++mi)
#pragma unroll
    for (int r = 0; r < 4; ++r) {
      float s = rsum[mi][r];
      s += __shfl_xor(s, 1);
      s += __shfl_xor(s, 2);
      s += __shfl_xor(s, 4);
      s += __shfl_xor(s, 8);
      if ((lane & 15) == 0)
        atomicAdd(&S_all[m0 + wr * 64 + mi * 16 + (lane >> 4) * 4 + r], s);
    }

  // ---- fused diagonal (blocks with by == bx>>1 only; r13/r15-verified) ---
  if (by == (bx >> 1)) {
#pragma unroll
    for (int mi = 0; mi < 4; ++mi) {
      const int R0 = m0 + wr * 64 + mi * 16;  // rows R0..R0+15 share b_
      const int tc = ((R0 >> 5) << 4) - n0;   // diag col offset in tile
      if ((tc >> 6) == wc) {
        const int dn = (tc >> 4) & 3;
#pragma unroll
        for (int ni = 0; ni < 4; ++ni)
          if (ni == dn) {
#pragma unroll
            for (int r = 0; r < 4; ++r) {
              float v = acc[mi][ni][r];
              v = v > 0.0f ? v : 0.0f;
              float vm = (v == 1.0f) ? 0.0f : v;
              float ps = v, ds = vm;
              ps += __shfl_xor(ps, 1); ds += __shfl_xor(ds, 1);
              ps += __shfl_xor(ps, 2); ds += __shfl_xor(ds, 2);
              ps += __shfl_xor(ps, 4); ds += __shfl_xor(ds, 4);
              ps += __shfl_xor(ps, 8); ds += __shfl_xor(ds, 8);
              if ((lane & 15) == 0) {
                const int R = R0 + (lane >> 4) * 4 + r;
                pos[R] = ps;
                diagm[R] = ds;
              }
            }
          }
      }
    }
  }

  // ---- last-block loss reduction (fused grl_final) ----------------------
  // Release: make this block's S_all atomics + pos/diagm stores visible,
  // then bump the counter. The block observing NBLOCKS-1 has acquire-seen
  // all 2047 prior releases -> safe to read everything.
  __syncthreads();
  if (tid == 0) {
    __threadfence();
    lastFlag = atomicAdd(counter, 1u);
  }
  __syncthreads();
  if (lastFlag == NBLOCKS - 1) {
    __threadfence();  // acquire side
    float s = 0.0f;
    for (int r = tid; r < M_TOT; r += 256) {
      const float neg = (S_all[r] - diagm[r]) / 255.0f;  // 255+1e-8 == 255.0f
      float rank = neg - pos[r] + 0.2f;
      rank = rank > 0.0f ? rank : 0.0f;
      s += rank * mask[r];
    }
#pragma unroll
    for (int off = 1; off < 64; off <<= 1) s += __shfl_xor(s, off);
    if (lane == 0) red[wid] = s;
    __syncthreads();
    if (tid == 0)
      out[0] = (red[0] + red[1] + red[2] + red[3]) / 256.0f;  // BETA*sum/B
  }
}

// ---------------------------------------------------------------------------
extern "C" void kernel_launch(void* const* d_in, const int* in_sizes, int n_in,
                              void* d_out, int out_size, void* d_ws, size_t ws_size,
                              hipStream_t stream) {
  const float* face = (const float*)d_in[0];
  const float* ner = (const float*)d_in[1];

  unsigned short* face_bf = (unsigned short*)d_ws;
  unsigned short* ner_bf = face_bf + (size_t)M_TOT * DIM_D;
  float* S_all = (float*)(ner_bf + (size_t)N_TOT * DIM_D);
  float* diagm = S_all + M_TOT;
  float* pos = diagm + M_TOT;
  float* mask = pos + M_TOT;
  unsigned int* counter = (unsigned int*)(mask + M_TOT);

  cvt_all<<<(M_TOT + N_TOT) / 4, 256, 0, stream>>>(face, ner, face_bf, ner_bf,
                                                   mask, S_all, counter);
  grl_gemm_bf16<<<dim3(M_TOT / 128, N_TOT / 128), 256, 0, stream>>>(
      face_bf, ner_bf, S_all, pos, diagm, mask, counter, (float*)d_out);
}

// Round 19
// 63.051 us; speedup vs baseline: 1.5966x; 1.5966x over previous
//
#include <hip/hip_runtime.h>

// B=256, F=32, N=16, D=512
//   sims[b,f,c,n] = relu(face[b,f]·ner[c,n])      (8192 x 4096 NT GEMM, K=512)
//   S_all[b,f]    = sum_{c,n} masked(sims)        (masked: ==1.0 -> 0)
//   pos[b,f]      = sum_n sims[b,f,b,n]           (unmasked diagonal)
//   diag_m[b,f]   = sum_n masked(sims[b,f,b,n])
//   loss = sum(relu((S_all-diag_m)/255 - pos + 0.2) * face_mask) / 256
//
// Round 19: REVERT to r15 (best measured: 63.19 us total, absmax 0.0).
// r18's last-block fusion regressed the GEMM 61.5 -> 101 us (device-scope
// fence + counter atomic serialized block exits and perturbed codegen).
// r15 = r2's GEMM core (61 us, MfmaUtil ~22%, 0 bank conflicts) + fused
// rowsum/diag epilogue + merged cvt(+mask+memset) + 1024-thread final.

#define DIM_D 512
#define M_TOT 8192
#define N_TOT 4096

typedef __attribute__((ext_vector_type(8))) short short8v;
typedef __attribute__((ext_vector_type(4))) float f32x4;

__device__ __forceinline__ unsigned short f2bf(float f) {
  unsigned int u = __builtin_bit_cast(unsigned int, f);
  u += 0x7fffu + ((u >> 16) & 1u);
  return (unsigned short)(u >> 16);
}

// ---------------------------------------------------------------------------
// Merged cvt: face+ner fp32 -> bf16, face_mask, and S_all zeroing.
// ---------------------------------------------------------------------------
__global__ __launch_bounds__(256) void cvt_all(
    const float* __restrict__ face, const float* __restrict__ ner,
    unsigned short* __restrict__ face_bf, unsigned short* __restrict__ ner_bf,
    float* __restrict__ mask, float* __restrict__ S_all) {
  if (blockIdx.x < 8) {  // 8 blocks x 256 thr x 4 floats = 8192 = S_all
    const int i = blockIdx.x * 1024 + threadIdx.x * 4;
    *(float4*)(S_all + i) = (float4){0.f, 0.f, 0.f, 0.f};
  }
  const int gw = blockIdx.x * 4 + (threadIdx.x >> 6);
  const int lane = threadIdx.x & 63;
  const bool isFace = gw < M_TOT;
  const int row = isFace ? gw : gw - M_TOT;
  const float* src = (isFace ? face : ner) + (size_t)row * DIM_D;
  unsigned short* dst = (isFace ? face_bf : ner_bf) + (size_t)row * DIM_D;

  const float4 f0 = ((const float4*)src)[lane * 2];
  const float4 f1 = ((const float4*)src)[lane * 2 + 1];
  short8v o;
  o[0] = (short)f2bf(f0.x); o[1] = (short)f2bf(f0.y);
  o[2] = (short)f2bf(f0.z); o[3] = (short)f2bf(f0.w);
  o[4] = (short)f2bf(f1.x); o[5] = (short)f2bf(f1.y);
  o[6] = (short)f2bf(f1.z); o[7] = (short)f2bf(f1.w);
  *(short8v*)(dst + lane * 8) = o;

  if (isFace) {
    float fs = f0.x + f0.y + f0.z + f0.w + f1.x + f1.y + f1.z + f1.w;
#pragma unroll
    for (int off = 1; off < 64; off <<= 1) fs += __shfl_xor(fs, off);
    if (lane == 0) mask[row] = (fs != 0.0f) ? 1.0f : 0.0f;
  }
}

// ---------------------------------------------------------------------------
// r2's GEMM core, byte-identical: 128x128 tile, BK=32, 4 waves (2x2),
// wave-tile 64x64 = 4x4 frags of 16x16. LDS 16 KB single-buffer.
// LDS: A/B tiles [128 rows][4 k-slots of 8 bf16], slot s of row r holds
// global k-block (s ^ ((r>>1)&3)); staged with global_load_lds w=16
// (dst linear, source pre-swizzled). Fused rowsum + diag epilogue.
// ---------------------------------------------------------------------------
#define MFMA(A_, B_, C_) __builtin_amdgcn_mfma_f32_16x16x32_bf16(A_, B_, C_, 0, 0, 0)

__global__ __launch_bounds__(256) void grl_gemm_bf16(
    const unsigned short* __restrict__ A, const unsigned short* __restrict__ Bn,
    float* __restrict__ S_all, float* __restrict__ pos,
    float* __restrict__ diagm) {
  __shared__ __align__(16) unsigned short As[128 * 32];
  __shared__ __align__(16) unsigned short Bs[128 * 32];

  const int tid = threadIdx.x;
  const int lane = tid & 63;
  const int wid = tid >> 6;
  const int wr = wid >> 1;        // wave row (0..1)
  const int wc = wid & 1;         // wave col (0..1)
  const int bx = blockIdx.x;
  const int by = blockIdx.y;
  const int m0 = bx * 128;
  const int n0 = by * 128;

  // ---- stager per-lane setup (2 instrs per matrix per wave) ----
  const int g = (lane & 3) ^ ((lane >> 3) & 3);
  const int r0 = wid * 32 + (lane >> 2);
  const int r1 = r0 + 16;
  const unsigned short* gA0 = A + (size_t)(m0 + r0) * DIM_D + g * 8;
  const unsigned short* gA1 = A + (size_t)(m0 + r1) * DIM_D + g * 8;
  const unsigned short* gB0 = Bn + (size_t)(n0 + r0) * DIM_D + g * 8;
  const unsigned short* gB1 = Bn + (size_t)(n0 + r1) * DIM_D + g * 8;
  unsigned short* lA0 = As + (wid * 2 + 0) * 512;   // wave-uniform LDS bases
  unsigned short* lA1 = As + (wid * 2 + 1) * 512;
  unsigned short* lB0 = Bs + (wid * 2 + 0) * 512;
  unsigned short* lB1 = Bs + (wid * 2 + 1) * 512;

  // ---- reader per-lane setup ----
  const int slotR = (lane >> 4) ^ ((lane >> 1) & 3);
  const int aoff = (lane & 15) * 32 + slotR * 8;   // in shorts (row stride 32)

  f32x4 acc[4][4];
#pragma unroll
  for (int i = 0; i < 4; ++i)
#pragma unroll
    for (int j = 0; j < 4; ++j) acc[i][j] = (f32x4){0.f, 0.f, 0.f, 0.f};

  for (int k0 = 0; k0 < DIM_D; k0 += 32) {
    __builtin_amdgcn_global_load_lds(
        (const __attribute__((address_space(1))) void*)(gA0 + k0),
        (__attribute__((address_space(3))) void*)lA0, 16, 0, 0);
    __builtin_amdgcn_global_load_lds(
        (const __attribute__((address_space(1))) void*)(gA1 + k0),
        (__attribute__((address_space(3))) void*)lA1, 16, 0, 0);
    __builtin_amdgcn_global_load_lds(
        (const __attribute__((address_space(1))) void*)(gB0 + k0),
        (__attribute__((address_space(3))) void*)lB0, 16, 0, 0);
    __builtin_amdgcn_global_load_lds(
        (const __attribute__((address_space(1))) void*)(gB1 + k0),
        (__attribute__((address_space(3))) void*)lB1, 16, 0, 0);
    __syncthreads();   // compiler drains vmcnt(0) here

    short8v af[4], bfr[4];
#pragma unroll
    for (int mi = 0; mi < 4; ++mi)
      af[mi] = *(const short8v*)(As + (wr * 64 + mi * 16) * 32 + aoff);
#pragma unroll
    for (int ni = 0; ni < 4; ++ni)
      bfr[ni] = *(const short8v*)(Bs + (wc * 64 + ni * 16) * 32 + aoff);
#pragma unroll
    for (int mi = 0; mi < 4; ++mi)
#pragma unroll
      for (int ni = 0; ni < 4; ++ni)
        acc[mi][ni] = MFMA(af[mi], bfr[ni], acc[mi][ni]);
    __syncthreads();
  }

  // ---- fused epilogue: relu, ==1->0, row sums ----
  // C/D layout (m89-verified): col = lane&15 (n), row = (lane>>4)*4 + reg
  float rsum[4][4];   // [mi][reg]
#pragma unroll
  for (int mi = 0; mi < 4; ++mi)
#pragma unroll
    for (int r = 0; r < 4; ++r) rsum[mi][r] = 0.0f;
#pragma unroll
  for (int mi = 0; mi < 4; ++mi)
#pragma unroll
    for (int ni = 0; ni < 4; ++ni)
#pragma unroll
      for (int r = 0; r < 4; ++r) {
        float v = acc[mi][ni][r];
        v = v > 0.0f ? v : 0.0f;
        v = (v == 1.0f) ? 0.0f : v;
        rsum[mi][r] += v;
      }

#pragma unroll
  for (int mi = 0; mi < 4; ++mi)
#pragma unroll
    for (int r = 0; r < 4; ++r) {
      float s = rsum[mi][r];
      s += __shfl_xor(s, 1);
      s += __shfl_xor(s, 2);
      s += __shfl_xor(s, 4);
      s += __shfl_xor(s, 8);
      if ((lane & 15) == 0)
        atomicAdd(&S_all[m0 + wr * 64 + mi * 16 + (lane >> 4) * 4 + r], s);
    }

  // ---- fused diagonal (blocks with by == bx>>1 only; r13-verified) ------
  if (by == (bx >> 1)) {
#pragma unroll
    for (int mi = 0; mi < 4; ++mi) {
      const int R0 = m0 + wr * 64 + mi * 16;  // rows R0..R0+15 share b_
      const int tc = ((R0 >> 5) << 4) - n0;   // diag col offset in tile
      if ((tc >> 6) == wc) {
        const int dn = (tc >> 4) & 3;
#pragma unroll
        for (int ni = 0; ni < 4; ++ni)
          if (ni == dn) {
#pragma unroll
            for (int r = 0; r < 4; ++r) {
              float v = acc[mi][ni][r];
              v = v > 0.0f ? v : 0.0f;
              float vm = (v == 1.0f) ? 0.0f : v;
              float ps = v, ds = vm;
              ps += __shfl_xor(ps, 1); ds += __shfl_xor(ds, 1);
              ps += __shfl_xor(ps, 2); ds += __shfl_xor(ds, 2);
              ps += __shfl_xor(ps, 4); ds += __shfl_xor(ds, 4);
              ps += __shfl_xor(ps, 8); ds += __shfl_xor(ds, 8);
              if ((lane & 15) == 0) {
                const int R = R0 + (lane >> 4) * 4 + r;
                pos[R] = ps;
                diagm[R] = ds;
              }
            }
          }
      }
    }
  }
}

// ---------------------------------------------------------------------------
// Finalize: rank + global sum. Single block, 1024 threads.
// ---------------------------------------------------------------------------
__global__ __launch_bounds__(1024) void grl_final(
    const float* __restrict__ S_all, const float* __restrict__ diagm,
    const float* __restrict__ pos, const float* __restrict__ mask,
    float* __restrict__ out) {
  __shared__ float red[16];
  const int lane = threadIdx.x & 63;
  const int wv = threadIdx.x >> 6;
  float s = 0.0f;
  for (int r = threadIdx.x; r < M_TOT; r += 1024) {
    const float neg = (S_all[r] - diagm[r]) / 255.0f;  // 255 + 1e-8 == 255.0f
    float rank = neg - pos[r] + 0.2f;
    rank = rank > 0.0f ? rank : 0.0f;
    s += rank * mask[r];
  }
#pragma unroll
  for (int off = 1; off < 64; off <<= 1) s += __shfl_xor(s, off);
  if (lane == 0) red[wv] = s;
  __syncthreads();
  if (threadIdx.x == 0) {
    float t = 0.0f;
#pragma unroll
    for (int i = 0; i < 16; ++i) t += red[i];
    out[0] = t / 256.0f;  // BETA * sum / B
  }
}

// ---------------------------------------------------------------------------
extern "C" void kernel_launch(void* const* d_in, const int* in_sizes, int n_in,
                              void* d_out, int out_size, void* d_ws, size_t ws_size,
                              hipStream_t stream) {
  const float* face = (const float*)d_in[0];
  const float* ner = (const float*)d_in[1];

  unsigned short* face_bf = (unsigned short*)d_ws;
  unsigned short* ner_bf = face_bf + (size_t)M_TOT * DIM_D;
  float* S_all = (float*)(ner_bf + (size_t)N_TOT * DIM_D);
  float* diagm = S_all + M_TOT;
  float* pos = diagm + M_TOT;
  float* mask = pos + M_TOT;

  cvt_all<<<(M_TOT + N_TOT) / 4, 256, 0, stream>>>(face, ner, face_bf, ner_bf,
                                                   mask, S_all);
  grl_gemm_bf16<<<dim3(M_TOT / 128, N_TOT / 128), 256, 0, stream>>>(
      face_bf, ner_bf, S_all, pos, diagm);
  grl_final<<<1, 1024, 0, stream>>>(S_all, diagm, pos, mask, (float*)d_out);
}